// Round 5
// baseline (921.918 us; speedup 1.0000x reference)
//
#include <hip/hip_runtime.h>
#include <hip/hip_bf16.h>
#include <stdint.h>
#include <math.h>

// MoE: x[4,2048,1024] fp32, Wg[1024,8], bg[8], W1[8,1024,4096], b1[8,4096],
//      W2[8,4096,1024], b2[8,1024].  top-2 of softmax over 8 experts, no renorm.
// fp32 gating -> counting-sort routing -> routed bf16 MFMA grouped GEMMs.
// GEMM: 256x256 tile, 8 waves (2Mx4N, per-wave 128x64 = acc[8][4]), BK=64,
// 8-phase-style schedule (T3+T4): per K-tile 4 phases of
//   {ds_read quadrant | stage half-tiles of next K-tile into buf^1 ->
//    s_barrier -> setprio(1) 16 MFMA setprio(0) -> s_barrier},
// ONE vmcnt(0) per K-tile after the last MFMA cluster (staging overlaps ~3
// compute phases; R1's 2-barrier loop had zero overlap).  128 KB LDS dbuf,
// 1 block/CU -- the schedule, not TLP, hides latency (R4 showed TLP loss
// kills the 2-barrier structure; R2 showed counted-vmcnt needs phase-split).
// global_load_lds w=16, XOR-swizzled source (slot s of row r holds chunk
// s^(r&7); read slot g^(r&7) inverts since read row&7 == r&7).
// M-tiles are 256 rows with a valid-row mask (segments stay 128-aligned;
// clamped A reads + masked writes handle expert-boundary overhang).
// GEMM2 split-K=2 for tail (576 blocks on 256 CUs; bias from K-half 0 only).

#define TOKENS   8192
#define DIM      1024
#define HIDN     4096
#define NEXP     8
#define PAIRS    (TOKENS * 2)                 // 16384
#define ROWCAP   17408                        // xe/hid row capacity (128-aligned segs <= 17400)
#define MAXT256  72                           // sum ceil(seg128/256) <= 64+8; 72 = 8*9 (XCD swizzle)
#define NHB      128                          // histogram blocks (128 pairs each)

typedef __attribute__((ext_vector_type(8))) short short8;   // 8 x bf16 = 4 VGPRs
typedef __attribute__((ext_vector_type(4))) float f32x4;

#define AS1 __attribute__((address_space(1)))
#define AS3 __attribute__((address_space(3)))

__device__ inline short bf16b(float f) {
    __hip_bfloat16 h = __float2bfloat16(f);
    return *reinterpret_cast<short*>(&h);
}

// ---------------------------------------------------------------- gating ----
__global__ __launch_bounds__(256) void gating_kernel(
    const float* __restrict__ x, const float* __restrict__ Wg,
    const float* __restrict__ bg,
    int* __restrict__ topk_e, float* __restrict__ topk_w)
{
    int t    = blockIdx.x * 4 + (threadIdx.x >> 6);
    int lane = threadIdx.x & 63;
    if (t >= TOKENS) return;
    const float* xr = x + (size_t)t * DIM;

    float acc[8];
#pragma unroll
    for (int e = 0; e < 8; ++e) acc[e] = 0.f;

#pragma unroll 4
    for (int j = 0; j < DIM / 64; ++j) {
        int idx = j * 64 + lane;
        float xv = xr[idx];
        const float* wr = Wg + (size_t)idx * 8;
        float4 w0 = *(const float4*)(wr);
        float4 w1 = *(const float4*)(wr + 4);
        acc[0] += xv * w0.x; acc[1] += xv * w0.y;
        acc[2] += xv * w0.z; acc[3] += xv * w0.w;
        acc[4] += xv * w1.x; acc[5] += xv * w1.y;
        acc[6] += xv * w1.z; acc[7] += xv * w1.w;
    }
#pragma unroll
    for (int off = 32; off > 0; off >>= 1)
#pragma unroll
        for (int e = 0; e < 8; ++e) acc[e] += __shfl_down(acc[e], off);

    if (lane == 0) {
        float lg[8];
#pragma unroll
        for (int e = 0; e < 8; ++e) lg[e] = acc[e] + bg[e];
        float mx = lg[0];
#pragma unroll
        for (int e = 1; e < 8; ++e) mx = fmaxf(mx, lg[e]);
        float p[8]; float s = 0.f;
#pragma unroll
        for (int e = 0; e < 8; ++e) { p[e] = expf(lg[e] - mx); s += p[e]; }
        int e0 = 0;
#pragma unroll
        for (int e = 1; e < 8; ++e) if (p[e] > p[e0]) e0 = e;
        int e1 = -1;
#pragma unroll
        for (int e = 0; e < 8; ++e)
            if (e != e0 && (e1 < 0 || p[e] > p[e1])) e1 = e;
        float inv = 1.f / s;
        topk_e[t * 2 + 0] = e0;  topk_w[t * 2 + 0] = p[e0] * inv;
        topk_e[t * 2 + 1] = e1;  topk_w[t * 2 + 1] = p[e1] * inv;
    }
}

// ------------------------------------------------------------------ hist ----
__global__ __launch_bounds__(128) void hist_kernel(
    const int* __restrict__ topk_e, int* __restrict__ hist)
{
    __shared__ int h[8];
    int t = threadIdx.x, b = blockIdx.x;
    if (t < 8) h[t] = 0;
    __syncthreads();
    atomicAdd(&h[topk_e[b * 128 + t]], 1);
    __syncthreads();
    if (t < 8) hist[b * 8 + t] = h[t];
}

// ------------------------------------------------------------------ plan ----
// scan hist -> per-block bases; 128-aligned expert segments; 256-row M-tile
// list with valid-row counts.  1 block x 128 threads.
__global__ __launch_bounds__(128) void plan_kernel(
    const int* __restrict__ hist, int* __restrict__ base,
    int* __restrict__ tile_e, int* __restrict__ tile_row0,
    int* __restrict__ tile_valid, int* __restrict__ n_tiles)
{
    __shared__ int sx[8][NHB];
    __shared__ int tot[8];
    __shared__ int segs[8];
    __shared__ int wtot[2];
    int t = threadIdx.x, lane = t & 63, wid = t >> 6;
#pragma unroll
    for (int e = 0; e < 8; ++e) {
        int hv = hist[t * 8 + e];
        int v = hv;
#pragma unroll
        for (int off = 1; off < 64; off <<= 1) {
            int n = __shfl_up(v, off);
            if (lane >= off) v += n;
        }
        if (lane == 63) wtot[wid] = v;
        __syncthreads();
        int incl = v + (wid ? wtot[0] : 0);
        sx[e][t] = incl - hv;
        if (t == NHB - 1) tot[e] = incl;
        __syncthreads();
    }
    if (t == 0) {
        int off = 0, nt = 0;
        for (int e = 0; e < 8; ++e) {
            segs[e] = off;
            int len = ((tot[e] + 127) >> 7) << 7;      // 128-aligned segment length
            int tl  = (len + 255) >> 8;                // 256-row tiles (last may overhang)
            for (int i = 0; i < tl; ++i) {
                tile_e[nt]     = e;
                tile_row0[nt]  = off + i * 256;
                int v          = len - i * 256;
                tile_valid[nt] = v > 256 ? 256 : v;
                ++nt;
            }
            off += len;
        }
        *n_tiles = nt;
    }
    __syncthreads();
#pragma unroll
    for (int e = 0; e < 8; ++e) base[t * 8 + e] = segs[e] + sx[e][t];
}

// ----------------------------------------------------------- gather rank ----
__global__ __launch_bounds__(128) void gather_rank(
    const int* __restrict__ topk_e, const float* __restrict__ topk_w,
    const int* __restrict__ base, int* __restrict__ pair_row,
    int* __restrict__ row_token, float* __restrict__ row_gate)
{
    __shared__ int cnt[8];
    int t = threadIdx.x, b = blockIdx.x;
    if (t < 8) cnt[t] = 0;
    __syncthreads();
    int pr = b * 128 + t;
    int e  = topk_e[pr];
    int lr = atomicAdd(&cnt[e], 1);
    int row = base[b * 8 + e] + lr;
    pair_row[pr]   = row;
    row_token[row] = pr >> 1;
    row_gate[row]  = topk_w[pr];
}

// ---------------------------------------------------------- scatter copy ----
__global__ __launch_bounds__(256) void scatter_copy(
    const float* __restrict__ x, const int* __restrict__ pair_row,
    __hip_bfloat16* __restrict__ xe)
{
    int b = blockIdx.x;
    int wv = threadIdx.x >> 6, lane = threadIdx.x & 63;
#pragma unroll 4
    for (int i = 0; i < 16; ++i) {
        int p   = b * 64 + i * 4 + wv;
        int row = pair_row[p];
        int tok = p >> 1;
        const float* xr = x + (size_t)tok * DIM;
        __hip_bfloat16* xo = xe + (size_t)row * DIM;
        int idx = lane * 16;
        float4 v0 = *(const float4*)(xr + idx);
        float4 v1 = *(const float4*)(xr + idx + 4);
        float4 v2 = *(const float4*)(xr + idx + 8);
        float4 v3 = *(const float4*)(xr + idx + 12);
        short8 o0, o1;
        o0[0] = bf16b(v0.x); o0[1] = bf16b(v0.y); o0[2] = bf16b(v0.z); o0[3] = bf16b(v0.w);
        o0[4] = bf16b(v1.x); o0[5] = bf16b(v1.y); o0[6] = bf16b(v1.z); o0[7] = bf16b(v1.w);
        o1[0] = bf16b(v2.x); o1[1] = bf16b(v2.y); o1[2] = bf16b(v2.z); o1[3] = bf16b(v2.w);
        o1[4] = bf16b(v3.x); o1[5] = bf16b(v3.y); o1[6] = bf16b(v3.z); o1[7] = bf16b(v3.w);
        *(short8*)(xo + idx)     = o0;
        *(short8*)(xo + idx + 8) = o1;
    }
}

// --------------------------------------------------- weight transpose+cvt ----
__global__ __launch_bounds__(256) void transpose_cvt_kernel(
    const float* __restrict__ src, __hip_bfloat16* __restrict__ dst,
    int rows, int cols)
{
    __shared__ float tile[32][33];
    int e  = blockIdx.z;
    const float* s = src + (size_t)e * rows * cols;
    __hip_bfloat16* d = dst + (size_t)e * rows * cols;
    int c0 = blockIdx.x * 32, r0 = blockIdx.y * 32;
    int tx = threadIdx.x & 31, ty = threadIdx.x >> 5;   // 32 x 8
#pragma unroll
    for (int j = 0; j < 4; ++j) {
        int rr = ty + j * 8;
        tile[rr][tx] = s[(size_t)(r0 + rr) * cols + c0 + tx];
    }
    __syncthreads();
    int t  = threadIdx.x;
    int cr = t >> 3;        // dst row within tile (0..31)
    int g  = t & 7;         // 4-elem group (0..7)
    ushort o[4];
#pragma unroll
    for (int j = 0; j < 4; ++j) o[j] = (ushort)bf16b(tile[g * 4 + j][cr]);
    *(uint2*)(d + (size_t)(c0 + cr) * rows + r0 + g * 4) = *(uint2*)o;
}

// ------------------------------------------------------------------ GEMM ----
// C[M,N] = A[M,K] * B[N,K]^T per expert 256-row tile.  See header comment.
// MODE 1: hid = bf16(relu(acc + b1))                (N = 4096, grid.z = 1)
// MODE 2: atomicAdd(out[token], gate*(acc [+ b2]))  (N = 1024, grid.z = 2 split-K)
template <int MODE>
__global__ __launch_bounds__(512, 2) void moe_gemm(
    const __hip_bfloat16* __restrict__ A,
    const __hip_bfloat16* __restrict__ Bw,       // [E][N][K]
    const float* __restrict__ bias,              // [E][N]
    const int* __restrict__ tile_e, const int* __restrict__ tile_row0,
    const int* __restrict__ tile_valid, const int* __restrict__ n_tiles,
    int K, int N,
    __hip_bfloat16* __restrict__ hid,
    const int* __restrict__ row_token, const float* __restrict__ row_gate,
    float* __restrict__ out)
{
    // XCD-aware bijective swizzle (72 = 8*9)
    int bx   = blockIdx.x;
    int tidx = (bx & 7) * (MAXT256 / 8) + (bx >> 3);
    if (tidx >= *n_tiles) return;
    int e     = tile_e[tidx];
    int m0    = tile_row0[tidx];
    int valid = tile_valid[tidx];
    int n0    = blockIdx.y * 256;
    const char* Ab = (const char*)A;
    const char* Bb = (const char*)(Bw + (size_t)e * N * K);

    // split-K (GEMM2): each z-part covers K/gridDim.z
    int klen  = K / (int)gridDim.z;
    int kbase = blockIdx.z * klen;
    int nkt   = klen >> 6;

    __shared__ __hip_bfloat16 lds[2][4][8192];  // [buf][A0,A1,B0,B1][128x64] = 128 KB

    int tid  = threadIdx.x;
    int w    = tid >> 6;          // wave 0..7
    int l    = tid & 63;
    int r    = l & 15;
    int quad = l >> 4;
    int subrow = l >> 3;                      // 0..7
    int cswz   = ((l & 7) ^ subrow) * 16;     // swizzled source byte col
    int rsw    = r & 7;
    int wm = (w >> 2) * 128;                  // 0 / 128
    int wn = (w & 3) * 64;                    // 0 / 64 / 128 / 192
    int aPart = wm >> 7;                      // 0/1  (A half this wave reads)
    int bPart = 2 + (wn >> 7);                // 2/3  (B half this wave reads)
    int bColBase = wn & 64;                   // row-in-half base for B fragments

    const size_t ldb = (size_t)K * 2;

    const f32x4 fzero = {0.f, 0.f, 0.f, 0.f};
    f32x4 acc[8][4];
#pragma unroll
    for (int fr = 0; fr < 8; ++fr)
#pragma unroll
        for (int fc = 0; fc < 4; ++fc) acc[fr][fc] = fzero;

    // stage half-tile P (0=A rows 0-127, 1=A rows 128-255, 2=B rows 0-127,
    // 3=B rows 128-255) of K-slice k0 into buffer buf.  2 loads/thread.
    auto STAGE = [&](int buf, int P, int k0) {
#pragma unroll
        for (int j = 0; j < 2; ++j) {
            int rloc = j * 64 + w * 8 + subrow;          // 0..127
            int rabs;
            const char* src;
            if (P < 2) {
                rabs = m0 + P * 128 + rloc;
                rabs = rabs < (ROWCAP - 1) ? rabs : (ROWCAP - 1);  // clamp overhang
                src  = Ab;
            } else {
                rabs = n0 + (P - 2) * 128 + rloc;
                src  = Bb;
            }
            const char* g = src + (size_t)rabs * ldb + (size_t)k0 * 2 + cswz;
            char* d = (char*)(&lds[buf][P][0]) + j * 8192 + w * 1024;  // +lane*16 implicit
            __builtin_amdgcn_global_load_lds((const AS1 void*)g, (AS3 void*)d, 16, 0, 0);
        }
    };

    // prologue: K-tile 0 -> buf0, drain once
    STAGE(0, 0, kbase); STAGE(0, 1, kbase); STAGE(0, 2, kbase); STAGE(0, 3, kbase);
    asm volatile("s_waitcnt vmcnt(0)" ::: "memory");
    __builtin_amdgcn_s_barrier();

    for (int t = 0; t < nkt; ++t) {
        int buf = t & 1;
        int kn  = kbase + ((t + 1) << 6);
        bool pre = (t + 1 < nkt);
        const char* ldsA = (const char*)&lds[buf][aPart][0];
        const char* ldsB = (const char*)&lds[buf][bPart][0];
        short8 bF[4][2];
#pragma unroll
        for (int p = 0; p < 4; ++p) {
            if (p == 0) {
#pragma unroll
                for (int fc = 0; fc < 4; ++fc)
#pragma unroll
                    for (int kk = 0; kk < 2; ++kk)
                        bF[fc][kk] = *(const short8*)(ldsB
                            + (bColBase + fc * 16 + r) * 128
                            + (((kk * 4 + quad) ^ rsw) * 16));
            }
            short8 aF[2][2];
#pragma unroll
            for (int fi = 0; fi < 2; ++fi)
#pragma unroll
                for (int kk = 0; kk < 2; ++kk)
                    aF[fi][kk] = *(const short8*)(ldsA
                        + ((p * 2 + fi) * 16 + r) * 128
                        + (((kk * 4 + quad) ^ rsw) * 16));
            if (pre) {
                if (p == 0) { STAGE(buf ^ 1, 0, kn); STAGE(buf ^ 1, 1, kn); }
                if (p == 1) { STAGE(buf ^ 1, 2, kn); STAGE(buf ^ 1, 3, kn); }
            }
            __builtin_amdgcn_s_barrier();
            __builtin_amdgcn_s_setprio(1);
#pragma unroll
            for (int fi = 0; fi < 2; ++fi)
#pragma unroll
                for (int fc = 0; fc < 4; ++fc)
#pragma unroll
                    for (int kk = 0; kk < 2; ++kk)
                        acc[p * 2 + fi][fc] = __builtin_amdgcn_mfma_f32_16x16x32_bf16(
                            aF[fi][kk], bF[fc][kk], acc[p * 2 + fi][fc], 0, 0, 0);
            __builtin_amdgcn_s_setprio(0);
            if (p == 3) {
                if (pre) asm volatile("s_waitcnt vmcnt(0)" ::: "memory");
                __builtin_amdgcn_s_barrier();               // next tile fully in LDS
                __builtin_amdgcn_sched_barrier(0);          // pin: no read hoisting
            } else {
                __builtin_amdgcn_s_barrier();
            }
        }
    }

    if (MODE == 1) {
#pragma unroll
        for (int fr = 0; fr < 8; ++fr) {
            int lrow = wm + fr * 16 + quad * 4;
#pragma unroll
            for (int i = 0; i < 4; ++i) {
                if (lrow + i < valid) {
                    size_t rb = (size_t)(m0 + lrow + i) * N;
#pragma unroll
                    for (int fc = 0; fc < 4; ++fc) {
                        int col = n0 + wn + fc * 16 + r;
                        float v = acc[fr][fc][i] + bias[e * N + col];
                        hid[rb + col] = __float2bfloat16(fmaxf(v, 0.f));
                    }
                }
            }
        }
    } else {
        bool addb = (blockIdx.z == 0);
#pragma unroll
        for (int fr = 0; fr < 8; ++fr) {
            int lrow = wm + fr * 16 + quad * 4;
#pragma unroll
            for (int i = 0; i < 4; ++i) {
                int row = m0 + lrow + i;
                if (lrow + i < valid) {
                    int token = row_token[row];
                    if ((unsigned)token < (unsigned)TOKENS) {
                        float g = row_gate[row];
                        float* orow = out + (size_t)token * DIM;
#pragma unroll
                        for (int fc = 0; fc < 4; ++fc) {
                            int col = n0 + wn + fc * 16 + r;
                            float v = acc[fr][fc][i] + (addb ? bias[e * N + col] : 0.f);
                            atomicAdd(orow + col, g * v);
                        }
                    }
                }
            }
        }
    }
}

// ---------------------------------------------------------------- launch ----
extern "C" void kernel_launch(void* const* d_in, const int* in_sizes, int n_in,
                              void* d_out, int out_size, void* d_ws, size_t ws_size,
                              hipStream_t stream) {
    const float* x  = (const float*)d_in[0];
    const float* Wg = (const float*)d_in[1];
    const float* bg = (const float*)d_in[2];
    const float* W1 = (const float*)d_in[3];
    const float* b1 = (const float*)d_in[4];
    const float* W2 = (const float*)d_in[5];
    const float* b2 = (const float*)d_in[6];
    float* out = (float*)d_out;

    // workspace layout (~313 MB)
    char* w = (char*)d_ws;
    int*   n_tiles    = (int*)(w + 0);
    int*   tile_e     = (int*)(w + 256);
    int*   tile_valid = (int*)(w + 1024);
    int*   tile_row0  = (int*)(w + 2048);
    int*   hist       = (int*)(w + 4096);                       // 4 KB
    int*   base       = (int*)(w + 8192);                       // 4 KB
    int*   topk_e     = (int*)(w + 12288);                      // 64 KB
    float* topk_w     = (float*)(w + 77824);                    // 64 KB
    int*   pair_row   = (int*)(w + 143360);                     // 64 KB
    int*   row_token  = (int*)(w + 208896);                     // 68 KB (17408 ints)
    float* row_gate   = (float*)(w + 278528);                   // 68 KB
    __hip_bfloat16* xe  = (__hip_bfloat16*)(w + 348160);        // 34.0 MB (17408 rows)
    __hip_bfloat16* hid = (__hip_bfloat16*)(w + 35999744ULL);   // 136.0 MB (17408 rows)
    __hip_bfloat16* W1b = (__hip_bfloat16*)(w + 178606080ULL);  // 67.1 MB
    __hip_bfloat16* W2b = (__hip_bfloat16*)(w + 245714944ULL);  // 67.1 MB
    // total: 312,823,808 bytes

    hipMemsetAsync(out, 0, (size_t)out_size * sizeof(float), stream);  // out = 0
    // determinism hardening for pad rows:
    hipMemsetAsync(row_token, 0xFF, 69632, stream);   // token = -1 (invalid)
    hipMemsetAsync(row_gate, 0, 69632, stream);       // gate = 0
    hipMemsetAsync(xe, 0, 35651584ULL, stream);       // pad A rows finite (0)

    gating_kernel<<<TOKENS / 4, 256, 0, stream>>>(x, Wg, bg, topk_e, topk_w);
    hist_kernel<<<NHB, 128, 0, stream>>>(topk_e, hist);
    plan_kernel<<<1, 128, 0, stream>>>(hist, base, tile_e, tile_row0, tile_valid, n_tiles);
    gather_rank<<<NHB, 128, 0, stream>>>(topk_e, topk_w, base, pair_row,
                                         row_token, row_gate);
    scatter_copy<<<256, 256, 0, stream>>>(x, pair_row, xe);

    // W1: [E][1024][4096] -> W1b [E][4096][1024]
    transpose_cvt_kernel<<<dim3(HIDN / 32, DIM / 32, NEXP), 256, 0, stream>>>(W1, W1b, DIM, HIDN);
    // W2: [E][4096][1024] -> W2b [E][1024][4096]
    transpose_cvt_kernel<<<dim3(DIM / 32, HIDN / 32, NEXP), 256, 0, stream>>>(W2, W2b, HIDN, DIM);

    // GEMM1: hid = relu(xe @ W1 + b1)     M=rows, K=1024, N=4096
    moe_gemm<1><<<dim3(MAXT256, HIDN / 256, 1), 512, 0, stream>>>(
        xe, W1b, b1, tile_e, tile_row0, tile_valid, n_tiles, DIM, HIDN,
        hid, nullptr, nullptr, nullptr);
    // GEMM2: out += gate * (hid @ W2 + b2) M=rows, K=4096 (split 2), N=1024
    moe_gemm<2><<<dim3(MAXT256, DIM / 256, 2), 512, 0, stream>>>(
        hid, W2b, b2, tile_e, tile_row0, tile_valid, n_tiles, HIDN, DIM,
        nullptr, row_token, row_gate, out);
}

// Round 7
// 907.982 us; speedup vs baseline: 1.0153x; 1.0153x over previous
//
#include <hip/hip_runtime.h>
#include <hip/hip_bf16.h>
#include <stdint.h>
#include <math.h>

// MoE: x[4,2048,1024] fp32, Wg[1024,8], bg[8], W1[8,1024,4096], b1[8,4096],
//      W2[8,4096,1024], b2[8,1024].  top-2 of softmax over 8 experts, no renorm.
// fp32 gating -> counting-sort routing -> routed bf16 MFMA grouped GEMMs.
// GEMM = R1 structure (best measured: 306 us/GEMM): 128x128 tile, 4 waves of
// 64x64 (acc[4][4]), __syncthreads 2-phase, global_load_lds w=16 -- with:
//  * BK=128 (halves the per-K-step vmcnt(0) drains; LDS 64KB still fits the
//    measured 2 blocks/CU, so m132's occupancy objection doesn't apply)
//  * XCD bijective blockIdx swizzle (R4-proven: FETCH 492->138 MB)
//  * LDS layout [half(128B)][row][8 slots]; slot s of row r holds chunk
//    s^(r&7) within its half; read slot (g&7)^(r&7), half g>>3 inverts it
//    (read rows satisfy row&7 == r&7).
// Structural ports (R2 counted-vmcnt 2-phase, R5 8-phase) both REGRESSED
// vs R1 -- the compiler/barrier drain dominates them at this shape; see log.

#define TOKENS   8192
#define DIM      1024
#define HIDN     4096
#define NEXP     8
#define PAIRS    (TOKENS * 2)                 // 16384
#define MAXROWS  (PAIRS + NEXP * 64)          // 16896
#define MAXTILES 136                          // 8*17 -- divisible by 8 (XCD swizzle)
#define NHB      128                          // histogram blocks (128 pairs each)

typedef __attribute__((ext_vector_type(8))) short short8;   // 8 x bf16 = 4 VGPRs
typedef __attribute__((ext_vector_type(4))) float f32x4;

#define AS1 __attribute__((address_space(1)))
#define AS3 __attribute__((address_space(3)))

__device__ inline short bf16b(float f) {
    __hip_bfloat16 h = __float2bfloat16(f);
    return *reinterpret_cast<short*>(&h);
}

// ---------------------------------------------------------------- gating ----
// one wave per token: 8 fp32 logits, softmax, top-2 (strict > keeps lowest
// index on ties, matching jax.lax.top_k). No global atomics.
__global__ __launch_bounds__(256) void gating_kernel(
    const float* __restrict__ x, const float* __restrict__ Wg,
    const float* __restrict__ bg,
    int* __restrict__ topk_e, float* __restrict__ topk_w)
{
    int t    = blockIdx.x * 4 + (threadIdx.x >> 6);
    int lane = threadIdx.x & 63;
    if (t >= TOKENS) return;
    const float* xr = x + (size_t)t * DIM;

    float acc[8];
#pragma unroll
    for (int e = 0; e < 8; ++e) acc[e] = 0.f;

#pragma unroll 4
    for (int j = 0; j < DIM / 64; ++j) {
        int idx = j * 64 + lane;
        float xv = xr[idx];
        const float* wr = Wg + (size_t)idx * 8;
        float4 w0 = *(const float4*)(wr);
        float4 w1 = *(const float4*)(wr + 4);
        acc[0] += xv * w0.x; acc[1] += xv * w0.y;
        acc[2] += xv * w0.z; acc[3] += xv * w0.w;
        acc[4] += xv * w1.x; acc[5] += xv * w1.y;
        acc[6] += xv * w1.z; acc[7] += xv * w1.w;
    }
#pragma unroll
    for (int off = 32; off > 0; off >>= 1)
#pragma unroll
        for (int e = 0; e < 8; ++e) acc[e] += __shfl_down(acc[e], off);

    if (lane == 0) {
        float lg[8];
#pragma unroll
        for (int e = 0; e < 8; ++e) lg[e] = acc[e] + bg[e];
        float mx = lg[0];
#pragma unroll
        for (int e = 1; e < 8; ++e) mx = fmaxf(mx, lg[e]);
        float p[8]; float s = 0.f;
#pragma unroll
        for (int e = 0; e < 8; ++e) { p[e] = expf(lg[e] - mx); s += p[e]; }
        int e0 = 0;
#pragma unroll
        for (int e = 1; e < 8; ++e) if (p[e] > p[e0]) e0 = e;
        int e1 = -1;
#pragma unroll
        for (int e = 0; e < 8; ++e)
            if (e != e0 && (e1 < 0 || p[e] > p[e1])) e1 = e;
        float inv = 1.f / s;
        topk_e[t * 2 + 0] = e0;  topk_w[t * 2 + 0] = p[e0] * inv;
        topk_e[t * 2 + 1] = e1;  topk_w[t * 2 + 1] = p[e1] * inv;
    }
}

// ------------------------------------------------------------------ hist ----
__global__ __launch_bounds__(128) void hist_kernel(
    const int* __restrict__ topk_e, int* __restrict__ hist)
{
    __shared__ int h[8];
    int t = threadIdx.x, b = blockIdx.x;
    if (t < 8) h[t] = 0;
    __syncthreads();
    atomicAdd(&h[topk_e[b * 128 + t]], 1);
    __syncthreads();
    if (t < 8) hist[b * 8 + t] = h[t];
}

// ------------------------------------------------------------------ plan ----
__global__ __launch_bounds__(128) void plan_kernel(
    const int* __restrict__ hist, int* __restrict__ base,
    int* __restrict__ tile_e, int* __restrict__ tile_row0, int* __restrict__ n_tiles)
{
    __shared__ int sx[8][NHB];
    __shared__ int tot[8];
    __shared__ int segs[8];
    __shared__ int wtot[2];
    int t = threadIdx.x, lane = t & 63, wid = t >> 6;
#pragma unroll
    for (int e = 0; e < 8; ++e) {
        int hv = hist[t * 8 + e];
        int v = hv;
#pragma unroll
        for (int off = 1; off < 64; off <<= 1) {
            int n = __shfl_up(v, off);
            if (lane >= off) v += n;
        }
        if (lane == 63) wtot[wid] = v;
        __syncthreads();
        int incl = v + (wid ? wtot[0] : 0);
        sx[e][t] = incl - hv;
        if (t == NHB - 1) tot[e] = incl;
        __syncthreads();
    }
    if (t == 0) {
        int off = 0, nt = 0;
        for (int e = 0; e < 8; ++e) {
            segs[e] = off;
            int tl = (tot[e] + 127) >> 7;
            for (int i = 0; i < tl; ++i) { tile_e[nt] = e; tile_row0[nt] = off + i * 128; ++nt; }
            off += tl * 128;
        }
        *n_tiles = nt;
    }
    __syncthreads();
#pragma unroll
    for (int e = 0; e < 8; ++e) base[t * 8 + e] = segs[e] + sx[e][t];
}

// ----------------------------------------------------------- gather rank ----
__global__ __launch_bounds__(128) void gather_rank(
    const int* __restrict__ topk_e, const float* __restrict__ topk_w,
    const int* __restrict__ base, int* __restrict__ pair_row,
    int* __restrict__ row_token, float* __restrict__ row_gate)
{
    __shared__ int cnt[8];
    int t = threadIdx.x, b = blockIdx.x;
    if (t < 8) cnt[t] = 0;
    __syncthreads();
    int pr = b * 128 + t;
    int e  = topk_e[pr];
    int lr = atomicAdd(&cnt[e], 1);
    int row = base[b * 8 + e] + lr;
    pair_row[pr]   = row;
    row_token[row] = pr >> 1;
    row_gate[row]  = topk_w[pr];
}

// ---------------------------------------------------------- scatter copy ----
__global__ __launch_bounds__(256) void scatter_copy(
    const float* __restrict__ x, const int* __restrict__ pair_row,
    __hip_bfloat16* __restrict__ xe)
{
    int b = blockIdx.x;
    int wv = threadIdx.x >> 6, lane = threadIdx.x & 63;
#pragma unroll 4
    for (int i = 0; i < 16; ++i) {
        int p   = b * 64 + i * 4 + wv;
        int row = pair_row[p];
        int tok = p >> 1;
        const float* xr = x + (size_t)tok * DIM;
        __hip_bfloat16* xo = xe + (size_t)row * DIM;
        int idx = lane * 16;
        float4 v0 = *(const float4*)(xr + idx);
        float4 v1 = *(const float4*)(xr + idx + 4);
        float4 v2 = *(const float4*)(xr + idx + 8);
        float4 v3 = *(const float4*)(xr + idx + 12);
        short8 o0, o1;
        o0[0] = bf16b(v0.x); o0[1] = bf16b(v0.y); o0[2] = bf16b(v0.z); o0[3] = bf16b(v0.w);
        o0[4] = bf16b(v1.x); o0[5] = bf16b(v1.y); o0[6] = bf16b(v1.z); o0[7] = bf16b(v1.w);
        o1[0] = bf16b(v2.x); o1[1] = bf16b(v2.y); o1[2] = bf16b(v2.z); o1[3] = bf16b(v2.w);
        o1[4] = bf16b(v3.x); o1[5] = bf16b(v3.y); o1[6] = bf16b(v3.z); o1[7] = bf16b(v3.w);
        *(short8*)(xo + idx)     = o0;
        *(short8*)(xo + idx + 8) = o1;
    }
}

// --------------------------------------------------- weight transpose+cvt ----
// src: [E][rows][cols] fp32 -> dst: [E][cols][rows] bf16.  float4 reads
// (16B/lane), 8B stores, <=2-way LDS conflicts ([32][33] pad).
__global__ __launch_bounds__(256) void transpose_cvt_kernel(
    const float* __restrict__ src, __hip_bfloat16* __restrict__ dst,
    int rows, int cols)
{
    __shared__ float tile[32][33];
    int e  = blockIdx.z;
    const float* s = src + (size_t)e * rows * cols;
    __hip_bfloat16* d = dst + (size_t)e * rows * cols;
    int c0 = blockIdx.x * 32, r0 = blockIdx.y * 32;
    int t  = threadIdx.x;
    int ty = t >> 3;            // row 0..31
    int tx = (t & 7) * 4;       // col group 0,4,..28
    float4 v = *(const float4*)(s + (size_t)(r0 + ty) * cols + c0 + tx);
    tile[ty][tx + 0] = v.x; tile[ty][tx + 1] = v.y;
    tile[ty][tx + 2] = v.z; tile[ty][tx + 3] = v.w;
    __syncthreads();
    int cr = t >> 3;        // dst row within tile (0..31)
    int g  = t & 7;         // 4-elem group (0..7)
    ushort o[4];
#pragma unroll
    for (int j = 0; j < 4; ++j) o[j] = (ushort)bf16b(tile[g * 4 + j][cr]);
    *(uint2*)(d + (size_t)(c0 + cr) * rows + r0 + g * 4) = *(uint2*)o;
}

// ------------------------------------------------------------------ GEMM ----
// C[M,N] = A[M,K] * B[N,K]^T per expert tile.  128x128 tile, BK=128,
// FOUR waves 2x2, each 64x64 (acc[4][4] of 16x16x32 MFMA).  __syncthreads
// 2-phase.  LDS per matrix: [2 halves(128B)][128 rows][8 slots x 16B] = 32KB.
// Staging chunk (c,h) = 8 rows x 128B contiguous: lane l -> row c*8+(l>>3),
// slot l&7 holding global chunk (l&7)^(l>>3) of half h.  Read: global chunk
// g=kk*4+quad -> half g>>3, slot (g&7)^(r&7)  (read row&7 == r&7).
// MODE 1: hid = bf16(relu(acc + b1))          (N = 4096)
// MODE 2: atomicAdd(out[token], gate*(acc+b2)) (N = 1024)
template <int MODE>
__global__ __launch_bounds__(256) void moe_gemm(
    const __hip_bfloat16* __restrict__ A,
    const __hip_bfloat16* __restrict__ Bw,       // [E][N][K]
    const float* __restrict__ bias,              // [E][N]
    const int* __restrict__ tile_e, const int* __restrict__ tile_row0,
    const int* __restrict__ n_tiles,
    int K, int N,
    __hip_bfloat16* __restrict__ hid,
    const int* __restrict__ row_token, const float* __restrict__ row_gate,
    float* __restrict__ out)
{
    // XCD-aware bijective swizzle (MAXTILES = 136 = 8*17): same-XCD blocks get
    // adjacent M-tiles (same expert, same n0) -> share B-panel in that L2.
    int bx   = blockIdx.x;
    int tidx = (bx & 7) * (MAXTILES / 8) + (bx >> 3);
    if (tidx >= *n_tiles) return;
    int e  = tile_e[tidx];
    int m0 = tile_row0[tidx];
    int n0 = blockIdx.y * 128;
    const __hip_bfloat16* Bb = Bw + (size_t)e * N * K;

    __shared__ __hip_bfloat16 lA[2 * 128 * 64];   // 32 KB  [half][row][64 bf16]
    __shared__ __hip_bfloat16 lB[2 * 128 * 64];   // 32 KB

    int tid  = threadIdx.x;
    int w    = tid >> 6;          // wave 0..3
    int l    = tid & 63;
    int r    = l & 15;
    int quad = l >> 4;
    int subrow = l >> 3;                      // staging row-in-chunk 0..7
    int cswz   = ((l & 7) ^ subrow) * 16;     // swizzled byte col within half
    int wm = (w >> 1) * 64;                   // wave row offset in tile
    int wn = (w & 1) * 64;                    // wave col offset in tile
    int rsw = r & 7;

    const f32x4 fzero = {0.f, 0.f, 0.f, 0.f};
    f32x4 acc[4][4];
#pragma unroll
    for (int mi = 0; mi < 4; ++mi)
#pragma unroll
        for (int ni = 0; ni < 4; ++ni) acc[mi][ni] = fzero;

    const size_t ldb = (size_t)K * 2;

    for (int k0 = 0; k0 < K; k0 += 128) {
        // stage A & B: 16 chunks each (8 rows x 256B row-pairs as 2 halves)
#pragma unroll
        for (int i = 0; i < 4; ++i) {
            int c   = i * 4 + w;               // chunk 0..15, wave-uniform
            int row = c * 8 + subrow;          // 0..127
            const char* gA = (const char*)A  + (size_t)(m0 + row) * ldb + (size_t)k0 * 2;
            const char* gB = (const char*)Bb + (size_t)(n0 + row) * ldb + (size_t)k0 * 2;
#pragma unroll
            for (int h = 0; h < 2; ++h) {
                char* sA = (char*)lA + h * 16384 + c * 1024;   // + lane*16 implicit
                char* sB = (char*)lB + h * 16384 + c * 1024;
                __builtin_amdgcn_global_load_lds((const AS1 void*)(gA + h * 128 + cswz), (AS3 void*)sA, 16, 0, 0);
                __builtin_amdgcn_global_load_lds((const AS1 void*)(gB + h * 128 + cswz), (AS3 void*)sB, 16, 0, 0);
            }
        }
        __syncthreads();
#pragma unroll
        for (int kk = 0; kk < 4; ++kk) {
            int hoff = (kk >> 1) * 16384;
            int slot = ((((kk & 1) * 4) + quad) ^ rsw) * 16;
            short8 aF[4], bF[4];
#pragma unroll
            for (int mi = 0; mi < 4; ++mi) {
                int row = wm + mi * 16 + r;
                aF[mi] = *(const short8*)((const char*)lA + hoff + row * 128 + slot);
            }
#pragma unroll
            for (int ni = 0; ni < 4; ++ni) {
                int row = wn + ni * 16 + r;
                bF[ni] = *(const short8*)((const char*)lB + hoff + row * 128 + slot);
            }
#pragma unroll
            for (int mi = 0; mi < 4; ++mi)
#pragma unroll
                for (int ni = 0; ni < 4; ++ni)
                    acc[mi][ni] = __builtin_amdgcn_mfma_f32_16x16x32_bf16(
                        aF[mi], bF[ni], acc[mi][ni], 0, 0, 0);
        }
        __syncthreads();
    }

    if (MODE == 1) {
#pragma unroll
        for (int mi = 0; mi < 4; ++mi)
#pragma unroll
            for (int i = 0; i < 4; ++i) {
                int row = m0 + wm + mi * 16 + quad * 4 + i;
                size_t rb = (size_t)row * N;
#pragma unroll
                for (int ni = 0; ni < 4; ++ni) {
                    int col = n0 + wn + ni * 16 + r;
                    float v = acc[mi][ni][i] + bias[e * N + col];
                    hid[rb + col] = __float2bfloat16(fmaxf(v, 0.f));
                }
            }
    } else {
#pragma unroll
        for (int mi = 0; mi < 4; ++mi)
#pragma unroll
            for (int i = 0; i < 4; ++i) {
                int row = m0 + wm + mi * 16 + quad * 4 + i;
                int token = row_token[row];
                if ((unsigned)token < (unsigned)TOKENS) {
                    float g = row_gate[row];
                    float* orow = out + (size_t)token * DIM;
#pragma unroll
                    for (int ni = 0; ni < 4; ++ni) {
                        int col = n0 + wn + ni * 16 + r;
                        float v = acc[mi][ni][i] + bias[e * N + col];
                        atomicAdd(orow + col, g * v);
                    }
                }
            }
    }
}

// ---------------------------------------------------------------- launch ----
extern "C" void kernel_launch(void* const* d_in, const int* in_sizes, int n_in,
                              void* d_out, int out_size, void* d_ws, size_t ws_size,
                              hipStream_t stream) {
    const float* x  = (const float*)d_in[0];
    const float* Wg = (const float*)d_in[1];
    const float* bg = (const float*)d_in[2];
    const float* W1 = (const float*)d_in[3];
    const float* b1 = (const float*)d_in[4];
    const float* W2 = (const float*)d_in[5];
    const float* b2 = (const float*)d_in[6];
    float* out = (float*)d_out;

    // workspace layout (~313 MB)
    char* w = (char*)d_ws;
    int*   n_tiles   = (int*)(w + 0);
    int*   tile_e    = (int*)(w + 256);
    int*   tile_row0 = (int*)(w + 2048);
    int*   hist      = (int*)(w + 4096);                       // 4 KB
    int*   base      = (int*)(w + 8192);                       // 4 KB
    int*   topk_e    = (int*)(w + 12288);                      // 64 KB
    float* topk_w    = (float*)(w + 77824);                    // 64 KB
    int*   pair_row  = (int*)(w + 143360);                     // 64 KB
    int*   row_token = (int*)(w + 208896);                     // 68 KB (17408 ints)
    float* row_gate  = (float*)(w + 278528);                   // 68 KB
    __hip_bfloat16* xe  = (__hip_bfloat16*)(w + 348160);       // 34.0 MB (17408 rows)
    __hip_bfloat16* hid = (__hip_bfloat16*)(w + 35999744ULL);  // 136.0 MB
    __hip_bfloat16* W1b = (__hip_bfloat16*)(w + 178606080ULL); // 67.1 MB
    __hip_bfloat16* W2b = (__hip_bfloat16*)(w + 245714944ULL); // 67.1 MB
    // total: 312,823,808 bytes

    hipMemsetAsync(out, 0, (size_t)out_size * sizeof(float), stream); // out = 0
    // pad-row hardening: token = -1 (invalid), gate = 0
    hipMemsetAsync(row_token, 0xFF, 69632, stream);
    hipMemsetAsync(row_gate, 0, 69632, stream);

    gating_kernel<<<TOKENS / 4, 256, 0, stream>>>(x, Wg, bg, topk_e, topk_w);
    hist_kernel<<<NHB, 128, 0, stream>>>(topk_e, hist);
    plan_kernel<<<1, 128, 0, stream>>>(hist, base, tile_e, tile_row0, n_tiles);
    gather_rank<<<NHB, 128, 0, stream>>>(topk_e, topk_w, base, pair_row,
                                         row_token, row_gate);
    scatter_copy<<<256, 256, 0, stream>>>(x, pair_row, xe);

    // W1: [E][1024][4096] -> W1b [E][4096][1024]
    transpose_cvt_kernel<<<dim3(HIDN / 32, DIM / 32, NEXP), 256, 0, stream>>>(W1, W1b, DIM, HIDN);
    // W2: [E][4096][1024] -> W2b [E][1024][4096]
    transpose_cvt_kernel<<<dim3(DIM / 32, HIDN / 32, NEXP), 256, 0, stream>>>(W2, W2b, HIDN, DIM);

    // GEMM1: hid = relu(xe @ W1 + b1)     M=rows, K=1024, N=4096
    moe_gemm<1><<<dim3(MAXTILES, HIDN / 128), 256, 0, stream>>>(
        xe, W1b, b1, tile_e, tile_row0, n_tiles, DIM, HIDN,
        hid, nullptr, nullptr, nullptr);
    // GEMM2: out += gate * (hid @ W2 + b2) M=rows, K=4096, N=1024
    moe_gemm<2><<<dim3(MAXTILES, DIM / 128), 256, 0, stream>>>(
        hid, W2b, b2, tile_e, tile_row0, n_tiles, HIDN, DIM,
        nullptr, row_token, row_gate, out);
}